// Round 9
// baseline (740.925 us; speedup 1.0000x reference)
//
#include <hip/hip_runtime.h>

#define IMG 512
#define OUT_HW 502
#define N_IMG 64
#define XT 8                        // x-tiles: 64 cols each (lane = column)
#define YT 12                       // y-tiles: 45 output rows each
#define OROWS 45                    // outputs per wave (55 input rows - 10)
#define NWAVE (XT * YT * N_IMG)     // 6144 partial sums

typedef float f4u __attribute__((ext_vector_type(4), aligned(4)));

// One wave (= one 64-thread block) owns a 64-col x 45-row output tile.
// Lane = column. H-conv from 3 unaligned dwordx4 loads per image per row;
// V-conv: 5x11 register ring, static indices. No LDS, no barriers.
__global__ __launch_bounds__(64, 6) void ssim_main(
    const float* __restrict__ g_a, const float* __restrict__ g_b,
    const float* __restrict__ g_w, float* __restrict__ bsum)
{
  const int lane = threadIdx.x;              // 0..63
  const int xt = blockIdx.x;                 // 0..7
  const int yt = blockIdx.y;                 // 0..11
  const int y0 = yt * OROWS;

  const float* __restrict__ A = g_a + (size_t)blockIdx.z * (IMG * IMG);
  const float* __restrict__ B = g_b + (size_t)blockIdx.z * (IMG * IMG);

  const int x = (xt << 6) | lane;            // 0..511
  const int xb = min(x, 500);                // 12-float window stays in-row
  const bool shift1 = (x == 501);            // window = offsets 1..11
  const bool xvalid = (x <= OUT_HW - 1);

  // exact rank-1 factor u of the Gaussian window: w[i][j] = u[i]*u[j]
  float u[11];
  {
    const float inv = 1.0f / sqrtf(g_w[5 * 11 + 5]);
#pragma unroll
    for (int j = 0; j < 11; ++j) u[j] = g_w[j * 11 + 5] * inv;
  }

  float win[5][11];                          // V sliding window (registers)
  float score = 0.f;

  for (int i = 0; i < 5; ++i) {              // 5 x 11 = 55 input rows
#pragma unroll
    for (int s = 0; s < 11; ++s) {
      const int r = 11 * i + s;              // ring slot == s (static)
      const int gy = min(y0 + r, IMG - 1);
      const float* pa = A + (gy << 9) + xb;
      const float* pb = B + (gy << 9) + xb;

      float a[12], b[12];
      {
        const f4u va0 = *(const f4u*)(pa);
        const f4u va1 = *(const f4u*)(pa + 4);
        const f4u va2 = *(const f4u*)(pa + 8);
        const f4u vb0 = *(const f4u*)(pb);
        const f4u vb1 = *(const f4u*)(pb + 4);
        const f4u vb2 = *(const f4u*)(pb + 8);
#pragma unroll
        for (int j = 0; j < 4; ++j) {
          a[j] = va0[j]; a[j + 4] = va1[j]; a[j + 8] = va2[j];
          b[j] = vb0[j]; b[j + 4] = vb1[j]; b[j + 8] = vb2[j];
        }
      }

      float h0 = 0.f, h1 = 0.f, h2 = 0.f, h3 = 0.f, h4 = 0.f;
#pragma unroll
      for (int j = 0; j < 11; ++j) {
        const float ta = u[j] * a[j], tb = u[j] * b[j];
        h0 += ta;
        h1 += tb;
        h2 = fmaf(ta, a[j], h2);
        h3 = fmaf(tb, b[j], h3);
        h4 = fmaf(ta, b[j], h4);
      }
      if (shift1) {                          // 1 lane per tile-7 wave
        h0 = h1 = h2 = h3 = h4 = 0.f;
#pragma unroll
        for (int j = 0; j < 11; ++j) {
          const float ta = u[j] * a[j + 1], tb = u[j] * b[j + 1];
          h0 += ta;
          h1 += tb;
          h2 = fmaf(ta, a[j + 1], h2);
          h3 = fmaf(tb, b[j + 1], h3);
          h4 = fmaf(ta, b[j + 1], h4);
        }
      }
      win[0][s] = h0; win[1][s] = h1; win[2][s] = h2;
      win[3][s] = h3; win[4][s] = h4;

      if (i > 0 || s == 10) {                // r >= 10: a V-window is full
        float o[5];
#pragma unroll
        for (int m = 0; m < 5; ++m) {
          float acc = 0.f;
#pragma unroll
          for (int k = 0; k < 11; ++k)       // oldest row at slot (s+1)%11
            acc = fmaf(u[k], win[m][(s + 1 + k) % 11], acc);
          o[m] = acc;
        }
        const int yo = y0 + r - 10;
        const bool valid = xvalid && (yo < OUT_HW);
        const float C1 = 1e-4f, C2 = 9e-4f;
        const float mu1 = o[0], mu2 = o[1];
        const float mu1s = mu1 * mu1, mu2s = mu2 * mu2, m12 = mu1 * mu2;
        const float sig1 = o[2] - mu1s, sig2 = o[3] - mu2s, sig12 = o[4] - m12;
        const float num = (2.f * m12 + C1) * (2.f * sig12 + C2);
        const float den = (mu1s + mu2s + C1) * (sig1 + sig2 + C2);
        const float val = num * __builtin_amdgcn_rcpf(den);
        score += valid ? val : 0.f;
      }
    }
  }

  // wave-level reduction, one float per wave
#pragma unroll
  for (int o = 32; o > 0; o >>= 1) score += __shfl_down(score, o);
  if (lane == 0) {
    const int widx = ((int)blockIdx.z * YT + yt) * XT + xt;
    bsum[widx] = score;
  }
}

__global__ __launch_bounds__(256) void ssim_final(
    const float* __restrict__ bsum, float* __restrict__ out)
{
  const float4* b4 = (const float4*)bsum;    // 1536 float4 = 6144 floats
  double v = 0.0;
#pragma unroll
  for (int k = 0; k < 6; ++k) {
    const float4 f = b4[k * 256 + threadIdx.x];
    v += (double)((f.x + f.y) + (f.z + f.w));
  }
#pragma unroll
  for (int off = 32; off > 0; off >>= 1) v += __shfl_down(v, off);
  __shared__ double s_red[4];
  const int wave = (int)threadIdx.x >> 6, lane = (int)threadIdx.x & 63;
  if (lane == 0) s_red[wave] = v;
  __syncthreads();
  if (threadIdx.x == 0) {
    const double total = s_red[0] + s_red[1] + s_red[2] + s_red[3];
    out[0] = (float)(total / (double)((size_t)N_IMG * OUT_HW * OUT_HW));
  }
}

extern "C" void kernel_launch(void* const* d_in, const int* in_sizes, int n_in,
                              void* d_out, int out_size, void* d_ws, size_t ws_size,
                              hipStream_t stream) {
  const float* yh = (const float*)d_in[0];
  const float* yy = (const float*)d_in[1];
  const float* w  = (const float*)d_in[2];
  float* bsum = (float*)d_ws;                // NWAVE floats = 24 KB
  float* out = (float*)d_out;

  dim3 grid(XT, YT, N_IMG);                  // 6144 one-wave blocks
  hipLaunchKernelGGL(ssim_main, grid, dim3(64), 0, stream, yh, yy, w, bsum);
  hipLaunchKernelGGL(ssim_final, dim3(1), dim3(256), 0, stream, bsum, out);
}

// Round 11
// 217.987 us; speedup vs baseline: 3.3989x; 3.3989x over previous
//
#include <hip/hip_runtime.h>

#define IMG 512
#define OUT_HW 502
#define N_IMG 64
#define XT 8                        // x-tiles: 64 cols each (lane = column)
#define YT 12                       // y-tiles: 45 output rows each
#define OROWS 45                    // outputs per wave (55 input rows - 10)
#define NWAVE (XT * YT * N_IMG)     // 6144 partial sums

// One wave (= one 64-thread block) owns a 64-col x 45-row output tile.
// Lane = column. H-conv: 11 scalar loads per image per row from base
// min(x,501) -- exactly the 11-tap window for every valid output column.
// V-conv: 5x11 register ring with static indices. No LDS, no barriers.
// NOTE: this structure needs ~70 VGPRs live; do NOT cap below (64,2) --
// launch_bounds(64,6) in R9 forced a spill collapse (VGPR 40, 456MB scratch).
__global__ __launch_bounds__(64, 2) void ssim_main(
    const float* __restrict__ g_a, const float* __restrict__ g_b,
    const float* __restrict__ g_w, float* __restrict__ bsum)
{
  const int lane = threadIdx.x;              // 0..63
  const int xt = blockIdx.x;                 // 0..7
  const int yt = blockIdx.y;                 // 0..11
  const int y0 = yt * OROWS;

  const float* __restrict__ A = g_a + (size_t)blockIdx.z * (IMG * IMG);
  const float* __restrict__ B = g_b + (size_t)blockIdx.z * (IMG * IMG);

  const int x = (xt << 6) | lane;            // 0..511
  const int xb = min(x, OUT_HW - 1);         // load base; max col 501+10=511
  const bool xvalid = (x <= OUT_HW - 1);

  // exact rank-1 factor u of the Gaussian window: w[i][j] = u[i]*u[j]
  float u[11];
  {
    const float inv = 1.0f / sqrtf(g_w[5 * 11 + 5]);
#pragma unroll
    for (int j = 0; j < 11; ++j) u[j] = g_w[j * 11 + 5] * inv;
  }

  float win[5][11];                          // V sliding window (registers)
  float score = 0.f;

  for (int i = 0; i < 5; ++i) {              // 5 x 11 = 55 input rows
#pragma unroll
    for (int s = 0; s < 11; ++s) {
      const int r = 11 * i + s;              // ring slot == s (static)
      const int gy = min(y0 + r, IMG - 1);
      const float* pa = A + (gy << 9) + xb;
      const float* pb = B + (gy << 9) + xb;
      float a[11], b[11];
#pragma unroll
      for (int j = 0; j < 11; ++j) {         // static idx -> VGPRs
        a[j] = pa[j];
        b[j] = pb[j];
      }

      float h0 = 0.f, h1 = 0.f, h2 = 0.f, h3 = 0.f, h4 = 0.f;
#pragma unroll
      for (int j = 0; j < 11; ++j) {
        const float ta = u[j] * a[j], tb = u[j] * b[j];
        h0 += ta;
        h1 += tb;
        h2 = fmaf(ta, a[j], h2);
        h3 = fmaf(tb, b[j], h3);
        h4 = fmaf(ta, b[j], h4);
      }
      win[0][s] = h0; win[1][s] = h1; win[2][s] = h2;
      win[3][s] = h3; win[4][s] = h4;

      if (i > 0 || s == 10) {                // r >= 10: a V-window is full
        float o[5];
#pragma unroll
        for (int m = 0; m < 5; ++m) {
          float acc = 0.f;
#pragma unroll
          for (int k = 0; k < 11; ++k)       // oldest row at slot (s+1)%11
            acc = fmaf(u[k], win[m][(s + 1 + k) % 11], acc);
          o[m] = acc;
        }
        const int yo = y0 + r - 10;
        const bool valid = xvalid && (yo < OUT_HW);
        const float C1 = 1e-4f, C2 = 9e-4f;
        const float mu1 = o[0], mu2 = o[1];
        const float mu1s = mu1 * mu1, mu2s = mu2 * mu2, m12 = mu1 * mu2;
        const float sig1 = o[2] - mu1s, sig2 = o[3] - mu2s, sig12 = o[4] - m12;
        const float num = (2.f * m12 + C1) * (2.f * sig12 + C2);
        const float den = (mu1s + mu2s + C1) * (sig1 + sig2 + C2);
        const float val = num * __builtin_amdgcn_rcpf(den);
        score += valid ? val : 0.f;
      }
    }
  }

  // wave-level reduction, one float per wave
#pragma unroll
  for (int o = 32; o > 0; o >>= 1) score += __shfl_down(score, o);
  if (lane == 0) {
    const int widx = ((int)blockIdx.z * YT + yt) * XT + xt;
    bsum[widx] = score;
  }
}

__global__ __launch_bounds__(256) void ssim_final(
    const float* __restrict__ bsum, float* __restrict__ out)
{
  const float4* b4 = (const float4*)bsum;    // 1536 float4 = 6144 floats
  double v = 0.0;
#pragma unroll
  for (int k = 0; k < 6; ++k) {
    const float4 f = b4[k * 256 + threadIdx.x];
    v += (double)((f.x + f.y) + (f.z + f.w));
  }
#pragma unroll
  for (int off = 32; off > 0; off >>= 1) v += __shfl_down(v, off);
  __shared__ double s_red[4];
  const int wave = (int)threadIdx.x >> 6, lane = (int)threadIdx.x & 63;
  if (lane == 0) s_red[wave] = v;
  __syncthreads();
  if (threadIdx.x == 0) {
    const double total = s_red[0] + s_red[1] + s_red[2] + s_red[3];
    out[0] = (float)(total / (double)((size_t)N_IMG * OUT_HW * OUT_HW));
  }
}

extern "C" void kernel_launch(void* const* d_in, const int* in_sizes, int n_in,
                              void* d_out, int out_size, void* d_ws, size_t ws_size,
                              hipStream_t stream) {
  const float* yh = (const float*)d_in[0];
  const float* yy = (const float*)d_in[1];
  const float* w  = (const float*)d_in[2];
  float* bsum = (float*)d_ws;                // NWAVE floats = 24 KB
  float* out = (float*)d_out;

  dim3 grid(XT, YT, N_IMG);                  // 6144 one-wave blocks
  hipLaunchKernelGGL(ssim_main, grid, dim3(64), 0, stream, yh, yy, w, bsum);
  hipLaunchKernelGGL(ssim_final, dim3(1), dim3(256), 0, stream, bsum, out);
}